// Round 10
// baseline (485.554 us; speedup 1.0000x reference)
//
#include <hip/hip_runtime.h>
#include <hip/hip_fp16.h>

#define NN 20000      // nodes
#define NE 320000     // edges
#define SS 2          // feature axis
#define FIN 128
#define FH 246

typedef _Float16 f16x8 __attribute__((ext_vector_type(8)));
typedef float f32x4 __attribute__((ext_vector_type(4)));

// ---------------- degree histogram ----------------
__global__ void degree_kernel(const int* __restrict__ src, const int* __restrict__ dst,
                              int* __restrict__ deg_out, int* __restrict__ deg_in) {
    int e = blockIdx.x * blockDim.x + threadIdx.x;
    if (e < NE) {
        atomicAdd(&deg_out[src[e]], 1);
        atomicAdd(&deg_in[dst[e]], 1);
    }
}

// ---------------- norms ----------------
__global__ void norm_kernel(const int* __restrict__ deg_out, const int* __restrict__ deg_in,
                            float* __restrict__ norm_out, float* __restrict__ norm_in) {
    int n = blockIdx.x * blockDim.x + threadIdx.x;
    if (n < NN) {
        norm_out[n] = rsqrtf(fmaxf((float)deg_out[n], 1.0f));
        norm_in[n]  = rsqrtf(fmaxf((float)deg_in[n], 1.0f));
    }
}

// ---------------- parallel CSR range allocation ----------------
__global__ void alloc_kernel(const int* __restrict__ deg_in, int* __restrict__ row_start,
                             int* __restrict__ cursor, int* __restrict__ counter) {
    __shared__ int smem[256];
    __shared__ int base_s;
    int tid = threadIdx.x;
    int i = blockIdx.x * 256 + tid;
    int v = (i < NN) ? deg_in[i] : 0;
    smem[tid] = v;
    __syncthreads();
    for (int off = 1; off < 256; off <<= 1) {
        int t = (tid >= off) ? smem[tid - off] : 0;
        __syncthreads();
        smem[tid] += t;
        __syncthreads();
    }
    int incl = smem[tid];
    if (tid == 0) base_s = atomicAdd(counter, smem[255]);
    __syncthreads();
    if (i < NN) {
        int excl = base_s + incl - v;
        row_start[i] = excl;
        cursor[i]    = excl;
    }
}

// ---------------- scatter edges into CSR ----------------
__global__ void scatter_kernel(const int* __restrict__ src, const int* __restrict__ dst,
                               int* __restrict__ cursor, int* __restrict__ sorted_src) {
    int e = blockIdx.x * blockDim.x + threadIdx.x;
    if (e < NE) {
        int d = dst[e];
        int pos = atomicAdd(&cursor[d], 1);
        sorted_src[pos] = src[e];
    }
}

// ---------------- W pre-split: Wt_hi/lo[n][k] = split_f16(W[k][n]), padded 256x256 ----------
__global__ void convert_w_split(const float* __restrict__ W,
                                ushort* __restrict__ Wh, ushort* __restrict__ Wl, int K) {
    int n = blockIdx.x, k = threadIdx.x;
    float v = (k < K && n < 246) ? W[k * 246 + n] : 0.f;
    _Float16 h = (_Float16)v;
    _Float16 l = (_Float16)(v - (float)h);
    Wh[n * 256 + k] = *(ushort*)&h;
    Wl[n * 256 + k] = *(ushort*)&l;
}

__global__ void init_out(float* __restrict__ out, const float* __restrict__ fcb) {
    int i = blockIdx.x * 256 + threadIdx.x;
    if (i < NN) out[i] = fcb[0];
}

// ---------------- chunk-tiled gather-aggregate, 512 B granularity ----------------
// agg[n,:] = sum_{e: dst=n} h[src,:]*norm_out[src]; node-row = F4ROW float4
// (64 = L0 feat, 128 = padded H rows; pads are zero in h so agg pads stay zero).
// 128 threads = 4 nodes x 32 lanes; lane owns float4 #(blockIdx.y*32+lane) of the
// row -> each gather reads 512 B contiguous. 4x edge unroll.
template<int F4ROW>
__global__ void aggregate2(const float* __restrict__ h,
                           const int* __restrict__ row_start,
                           const int* __restrict__ deg_in,
                           const int* __restrict__ sorted_src,
                           const float* __restrict__ norm_out,
                           float* __restrict__ agg) {
    int g  = threadIdx.x >> 5;              // 0..3: node sub-index
    int l  = threadIdx.x & 31;
    int n  = blockIdx.x * 4 + g;
    if (n >= NN) return;
    int idx = blockIdx.y * 32 + l;          // < F4ROW (F4ROW multiple of 32)
    const float4* hv = (const float4*)h;
    int beg = row_start[n];
    int end = beg + deg_in[n];
    float4 acc = {0.f, 0.f, 0.f, 0.f};
    int i = beg;
    for (; i + 4 <= end; i += 4) {
        int s0 = sorted_src[i + 0];
        int s1 = sorted_src[i + 1];
        int s2 = sorted_src[i + 2];
        int s3 = sorted_src[i + 3];
        float n0 = norm_out[s0], n1 = norm_out[s1];
        float n2 = norm_out[s2], n3 = norm_out[s3];
        float4 v0 = hv[(size_t)s0 * F4ROW + idx];
        float4 v1 = hv[(size_t)s1 * F4ROW + idx];
        float4 v2 = hv[(size_t)s2 * F4ROW + idx];
        float4 v3 = hv[(size_t)s3 * F4ROW + idx];
        acc.x += v0.x * n0 + v1.x * n1 + v2.x * n2 + v3.x * n3;
        acc.y += v0.y * n0 + v1.y * n1 + v2.y * n2 + v3.y * n3;
        acc.z += v0.z * n0 + v1.z * n1 + v2.z * n2 + v3.z * n3;
        acc.w += v0.w * n0 + v1.w * n1 + v2.w * n2 + v3.w * n3;
    }
    for (; i < end; ++i) {
        int s = sorted_src[i];
        float nr = norm_out[s];
        float4 v = hv[(size_t)s * F4ROW + idx];
        acc.x += v.x * nr;
        acc.y += v.y * nr;
        acc.z += v.z * nr;
        acc.w += v.w * nr;
    }
    ((float4*)agg)[(size_t)n * F4ROW + idx] = acc;
}

// ---------------- no-LDS split-f16 MFMA GEMM ----------------
// D[m,c] = relu( (A[m,:]*norm_in[m/2]) . W[:,c] + b[c] ), A fp32 [40000][KP]
// (KP = padded row stride 128|256; W k>=K pad is zero so A pad values are inert),
// W pre-split f16 hi/lo transposed+padded [256][256].
// Block = 4 waves, wave tile 32(m) x 64(n), block covers 32 x 256; grid 1250.
// A fragments loaded straight from global (8 contiguous fp32/lane) and split
// in-register; B fragments (16 B) straight from L2-resident Wt. NO LDS, NO
// barriers -> waves pipeline independently. acc += Ah*Wh + Al*Wh + Ah*Wl.
// Frag layouts identical to round-9 (validated, absmax 4.9e-4).
// FUSE: relu -> *fc_w -> 16-lane reduce -> atomicAdd(out[node], 0.5*p).
template<int KP, bool FUSE>
__global__ __launch_bounds__(256) void gemm_direct(const float* __restrict__ A,
                                                   const ushort* __restrict__ Wh,
                                                   const ushort* __restrict__ Wl,
                                                   const float* __restrict__ b,
                                                   const float* __restrict__ norm_in,
                                                   void* __restrict__ outv,
                                                   const float* __restrict__ fcw) {
    int tid  = threadIdx.x;
    int m0   = blockIdx.x * 32;
    int wave = tid >> 6, lane = tid & 63;
    int lr = lane & 15, quad = lane >> 4;

    f32x4 acc[2][4];
#pragma unroll
    for (int mi = 0; mi < 2; ++mi)
#pragma unroll
        for (int ni = 0; ni < 4; ++ni) acc[mi][ni] = {0.f, 0.f, 0.f, 0.f};

    const float* ap[2];
    float nrm[2];
#pragma unroll
    for (int mi = 0; mi < 2; ++mi) {
        int m = m0 + mi * 16 + lr;
        ap[mi]  = A + (size_t)m * KP;
        nrm[mi] = norm_in[m >> 1];
    }
    const ushort* wrow[4];
#pragma unroll
    for (int ni = 0; ni < 4; ++ni)
        wrow[ni] = (const ushort*)nullptr + (size_t)((wave * 64 + ni * 16 + lr) * 256);

    for (int kt = 0; kt < KP; kt += 32) {
        int ko = kt + quad * 8;
        f16x8 ah[2], al[2];
#pragma unroll
        for (int mi = 0; mi < 2; ++mi) {
            float4 f0 = *(const float4*)(ap[mi] + ko);
            float4 f1 = *(const float4*)(ap[mi] + ko + 4);
            float x[8] = {f0.x, f0.y, f0.z, f0.w, f1.x, f1.y, f1.z, f1.w};
#pragma unroll
            for (int j = 0; j < 8; ++j) {
                float v = x[j] * nrm[mi];
                _Float16 h = (_Float16)v;
                ah[mi][j] = h;
                al[mi][j] = (_Float16)(v - (float)h);
            }
        }
        f16x8 bh[4], bl[4];
#pragma unroll
        for (int ni = 0; ni < 4; ++ni) {
            size_t o = (size_t)(wrow[ni] - (const ushort*)nullptr) + ko;
            bh[ni] = *(const f16x8*)(Wh + o);
            bl[ni] = *(const f16x8*)(Wl + o);
        }
#pragma unroll
        for (int mi = 0; mi < 2; ++mi)
#pragma unroll
            for (int ni = 0; ni < 4; ++ni) {
                acc[mi][ni] = __builtin_amdgcn_mfma_f32_16x16x32_f16(ah[mi], bh[ni], acc[mi][ni], 0, 0, 0);
                acc[mi][ni] = __builtin_amdgcn_mfma_f32_16x16x32_f16(al[mi], bh[ni], acc[mi][ni], 0, 0, 0);
                acc[mi][ni] = __builtin_amdgcn_mfma_f32_16x16x32_f16(ah[mi], bl[ni], acc[mi][ni], 0, 0, 0);
            }
    }

    if (FUSE) {
        float* out = (float*)outv;
#pragma unroll
        for (int mi = 0; mi < 2; ++mi) {
#pragma unroll
            for (int i = 0; i < 4; ++i) {
                float p = 0.f;
#pragma unroll
                for (int ni = 0; ni < 4; ++ni) {
                    int c = wave * 64 + ni * 16 + lr;
                    if (c < 246)
                        p += fmaxf(acc[mi][ni][i] + b[c], 0.f) * fcw[c];
                }
#pragma unroll
                for (int off = 8; off > 0; off >>= 1)
                    p += __shfl_down(p, off, 16);
                if (lr == 0) {
                    int m = m0 + mi * 16 + quad * 4 + i;
                    atomicAdd(&out[m >> 1], 0.5f * p);
                }
            }
        }
    } else {
        float* outF = (float*)outv;    // fp32 [M][256], pads written 0
#pragma unroll
        for (int ni = 0; ni < 4; ++ni) {
            int c = wave * 64 + ni * 16 + lr;
            float bj = (c < 246) ? b[c] : 0.f;
#pragma unroll
            for (int mi = 0; mi < 2; ++mi)
#pragma unroll
                for (int i = 0; i < 4; ++i) {
                    int m = m0 + mi * 16 + quad * 4 + i;
                    float v = fmaxf(acc[mi][ni][i] + bj, 0.f);
                    if (c >= 246) v = 0.f;
                    outF[(size_t)m * 256 + c] = v;
                }
        }
    }
}

extern "C" void kernel_launch(void* const* d_in, const int* in_sizes, int n_in,
                              void* d_out, int out_size, void* d_ws, size_t ws_size,
                              hipStream_t stream) {
    const float* feat = (const float*)d_in[0];
    const int*   src  = (const int*)d_in[1];
    const int*   dst  = (const int*)d_in[2];
    const float* W0   = (const float*)d_in[3];
    const float* b0   = (const float*)d_in[4];
    const float* W1   = (const float*)d_in[5];
    const float* b1   = (const float*)d_in[6];
    const float* W2   = (const float*)d_in[7];
    const float* b2   = (const float*)d_in[8];
    const float* fcw  = (const float*)d_in[9];
    const float* fcb  = (const float*)d_in[10];
    float* out = (float*)d_out;

    char* ws = (char*)d_ws;
    size_t off = 0;
    auto alloc = [&](size_t bytes) {
        void* p = ws + off;
        off = (off + bytes + 255) & ~(size_t)255;
        return p;
    };
    int*    deg_out_i = (int*)alloc((2 * NN + 64) * sizeof(int));
    int*    deg_in_i  = deg_out_i + NN;
    int*    counter   = deg_out_i + 2 * NN;
    int*    row_start = (int*)alloc(NN * sizeof(int));
    int*    cursor    = (int*)alloc(NN * sizeof(int));
    int*    sorted    = (int*)alloc(NE * sizeof(int));
    float*  norm_out  = (float*)alloc(NN * sizeof(float));
    float*  norm_in   = (float*)alloc(NN * sizeof(float));
    ushort* Wh0 = (ushort*)alloc(256 * 256 * sizeof(ushort));
    ushort* Wl0 = (ushort*)alloc(256 * 256 * sizeof(ushort));
    ushort* Wh1 = (ushort*)alloc(256 * 256 * sizeof(ushort));
    ushort* Wl1 = (ushort*)alloc(256 * 256 * sizeof(ushort));
    ushort* Wh2 = (ushort*)alloc(256 * 256 * sizeof(ushort));
    ushort* Wl2 = (ushort*)alloc(256 * 256 * sizeof(ushort));
    float*  bufA = (float*)alloc((size_t)NN * SS * 256 * sizeof(float));  // agg out (padded)
    float*  bufH = (float*)alloc((size_t)NN * SS * 256 * sizeof(float));  // gemm out (padded)

    hipMemsetAsync(deg_out_i, 0, (2 * NN + 1) * sizeof(int), stream);

    degree_kernel<<<(NE + 255) / 256, 256, 0, stream>>>(src, dst, deg_out_i, deg_in_i);
    norm_kernel<<<(NN + 255) / 256, 256, 0, stream>>>(deg_out_i, deg_in_i, norm_out, norm_in);
    alloc_kernel<<<(NN + 255) / 256, 256, 0, stream>>>(deg_in_i, row_start, cursor, counter);
    scatter_kernel<<<(NE + 255) / 256, 256, 0, stream>>>(src, dst, cursor, sorted);

    convert_w_split<<<256, 256, 0, stream>>>(W0, Wh0, Wl0, FIN);
    convert_w_split<<<256, 256, 0, stream>>>(W1, Wh1, Wl1, FH);
    convert_w_split<<<256, 256, 0, stream>>>(W2, Wh2, Wl2, FH);
    init_out<<<(NN + 255) / 256, 256, 0, stream>>>(out, fcb);

    const int NB = (NN + 3) / 4;     // 5000
    const int GG = NN * SS / 32;     // 1250 gemm blocks

    // Layer 0: feat [N][2*128] -> agg(bufA, stride 128) -> gemm -> h1(bufH, stride 256)
    aggregate2<64><<<dim3(NB, 2), 128, 0, stream>>>(feat, row_start, deg_in_i, sorted, norm_out, bufA);
    gemm_direct<FIN, false><<<GG, 256, 0, stream>>>(bufA, Wh0, Wl0, b0, norm_in, bufH, fcw);

    // Layer 1: h1 -> agg(bufA, stride 256) -> gemm -> h2(bufH)
    aggregate2<128><<<dim3(NB, 4), 128, 0, stream>>>(bufH, row_start, deg_in_i, sorted, norm_out, bufA);
    gemm_direct<256, false><<<GG, 256, 0, stream>>>(bufA, Wh1, Wl1, b1, norm_in, bufH, fcw);

    // Layer 2: h2 -> agg(bufA) -> fused gemm -> out (atomicAdd; out pre-set to fcb)
    aggregate2<128><<<dim3(NB, 4), 128, 0, stream>>>(bufH, row_start, deg_in_i, sorted, norm_out, bufA);
    gemm_direct<256, true><<<GG, 256, 0, stream>>>(bufA, Wh2, Wl2, b2, norm_in, out, fcw);
}

// Round 11
// 408.785 us; speedup vs baseline: 1.1878x; 1.1878x over previous
//
#include <hip/hip_runtime.h>
#include <hip/hip_fp16.h>

#define NN 20000      // nodes
#define NE 320000     // edges
#define SS 2          // feature axis
#define FIN 128
#define FH 246

typedef _Float16 f16x8 __attribute__((ext_vector_type(8)));
typedef float f32x4 __attribute__((ext_vector_type(4)));

// ---------------- degree histogram ----------------
__global__ void degree_kernel(const int* __restrict__ src, const int* __restrict__ dst,
                              int* __restrict__ deg_out, int* __restrict__ deg_in) {
    int e = blockIdx.x * blockDim.x + threadIdx.x;
    if (e < NE) {
        atomicAdd(&deg_out[src[e]], 1);
        atomicAdd(&deg_in[dst[e]], 1);
    }
}

// ---------------- norms ----------------
__global__ void norm_kernel(const int* __restrict__ deg_out, const int* __restrict__ deg_in,
                            float* __restrict__ norm_out, float* __restrict__ norm_in) {
    int n = blockIdx.x * blockDim.x + threadIdx.x;
    if (n < NN) {
        norm_out[n] = rsqrtf(fmaxf((float)deg_out[n], 1.0f));
        norm_in[n]  = rsqrtf(fmaxf((float)deg_in[n], 1.0f));
    }
}

// ---------------- parallel CSR range allocation ----------------
__global__ void alloc_kernel(const int* __restrict__ deg_in, int* __restrict__ row_start,
                             int* __restrict__ cursor, int* __restrict__ counter) {
    __shared__ int smem[256];
    __shared__ int base_s;
    int tid = threadIdx.x;
    int i = blockIdx.x * 256 + tid;
    int v = (i < NN) ? deg_in[i] : 0;
    smem[tid] = v;
    __syncthreads();
    for (int off = 1; off < 256; off <<= 1) {
        int t = (tid >= off) ? smem[tid - off] : 0;
        __syncthreads();
        smem[tid] += t;
        __syncthreads();
    }
    int incl = smem[tid];
    if (tid == 0) base_s = atomicAdd(counter, smem[255]);
    __syncthreads();
    if (i < NN) {
        int excl = base_s + incl - v;
        row_start[i] = excl;
        cursor[i]    = excl;
    }
}

// ---------------- scatter edges into CSR ----------------
__global__ void scatter_kernel(const int* __restrict__ src, const int* __restrict__ dst,
                               int* __restrict__ cursor, int* __restrict__ sorted_src) {
    int e = blockIdx.x * blockDim.x + threadIdx.x;
    if (e < NE) {
        int d = dst[e];
        int pos = atomicAdd(&cursor[d], 1);
        sorted_src[pos] = src[e];
    }
}

// ---------------- W pre-split: Wt_hi/lo[n][k] = split_f16(W[k][n]), padded 256x256 ----------
__global__ void convert_w_split(const float* __restrict__ W,
                                ushort* __restrict__ Wh, ushort* __restrict__ Wl, int K) {
    int n = blockIdx.x, k = threadIdx.x;
    float v = (k < K && n < 246) ? W[k * 246 + n] : 0.f;
    _Float16 h = (_Float16)v;
    _Float16 l = (_Float16)(v - (float)h);
    Wh[n * 256 + k] = *(ushort*)&h;
    Wl[n * 256 + k] = *(ushort*)&l;
}

__global__ void init_out(float* __restrict__ out, const float* __restrict__ fcb) {
    int i = blockIdx.x * 256 + threadIdx.x;
    if (i < NN) out[i] = fcb[0];
}

// ---------------- chunk-tiled gather-aggregate, 512 B granularity (round-10, good) --------
template<int F4ROW>
__global__ void aggregate2(const float* __restrict__ h,
                           const int* __restrict__ row_start,
                           const int* __restrict__ deg_in,
                           const int* __restrict__ sorted_src,
                           const float* __restrict__ norm_out,
                           float* __restrict__ agg) {
    int g  = threadIdx.x >> 5;              // 0..3: node sub-index
    int l  = threadIdx.x & 31;
    int n  = blockIdx.x * 4 + g;
    if (n >= NN) return;
    int idx = blockIdx.y * 32 + l;          // < F4ROW (F4ROW multiple of 32)
    const float4* hv = (const float4*)h;
    int beg = row_start[n];
    int end = beg + deg_in[n];
    float4 acc = {0.f, 0.f, 0.f, 0.f};
    int i = beg;
    for (; i + 4 <= end; i += 4) {
        int s0 = sorted_src[i + 0];
        int s1 = sorted_src[i + 1];
        int s2 = sorted_src[i + 2];
        int s3 = sorted_src[i + 3];
        float n0 = norm_out[s0], n1 = norm_out[s1];
        float n2 = norm_out[s2], n3 = norm_out[s3];
        float4 v0 = hv[(size_t)s0 * F4ROW + idx];
        float4 v1 = hv[(size_t)s1 * F4ROW + idx];
        float4 v2 = hv[(size_t)s2 * F4ROW + idx];
        float4 v3 = hv[(size_t)s3 * F4ROW + idx];
        acc.x += v0.x * n0 + v1.x * n1 + v2.x * n2 + v3.x * n3;
        acc.y += v0.y * n0 + v1.y * n1 + v2.y * n2 + v3.y * n3;
        acc.z += v0.z * n0 + v1.z * n1 + v2.z * n2 + v3.z * n3;
        acc.w += v0.w * n0 + v1.w * n1 + v2.w * n2 + v3.w * n3;
    }
    for (; i < end; ++i) {
        int s = sorted_src[i];
        float nr = norm_out[s];
        float4 v = hv[(size_t)s * F4ROW + idx];
        acc.x += v.x * nr;
        acc.y += v.y * nr;
        acc.z += v.z * nr;
        acc.w += v.w * nr;
    }
    ((float4*)agg)[(size_t)n * F4ROW + idx] = acc;
}

// ---------------- LDS-staged split-f16 MFMA GEMM (round-9 structure, padded K) ----------
// D[m,c] = relu( (A[m,:]*norm_in[m/2]) . W[:,c] + b[c] )
// A fp32 [40000][KP] (KP=128|256, k-pads zero), W pre-split f16 hi/lo [256][256]
// (k-pads zero -> NO boundary code in the K loop). Block 64M x 128N, 4 waves 2x2,
// wave tile 32x64 via 2x4 mfma_f32_16x16x32_f16; acc += Ah*Wh + Al*Wh + Ah*Wl.
// Grid (625, 2). Frag layouts validated rounds 8-10 (absmax 4.9e-4).
// FUSE: relu -> *fc_w -> mean_s -> 16-lane reduce -> atomicAdd(out[node], 0.5p).
template<int KP, bool FUSE>
__global__ __launch_bounds__(256) void gemm_split(const float* __restrict__ A,
                                                  const ushort* __restrict__ Wh,
                                                  const ushort* __restrict__ Wl,
                                                  const float* __restrict__ b,
                                                  const float* __restrict__ norm_in,
                                                  void* __restrict__ outv,
                                                  const float* __restrict__ fcw) {
    constexpr int NT = KP / 32;
    __shared__ __align__(16) _Float16 Ah_s[64][40];
    __shared__ __align__(16) _Float16 Al_s[64][40];
    __shared__ __align__(16) _Float16 Bh_s[128][40];
    __shared__ __align__(16) _Float16 Bl_s[128][40];

    int tid  = threadIdx.x;
    int m0   = blockIdx.x * 64;
    int n0   = blockIdx.y * 128;
    int wave = tid >> 6, lane = tid & 63;
    int wm = wave >> 1, wn = wave & 1;
    int lr = lane & 15, quad = lane >> 4;

    f32x4 acc[2][4];
#pragma unroll
    for (int mi = 0; mi < 2; ++mi)
#pragma unroll
        for (int ni = 0; ni < 4; ++ni) acc[mi][ni] = {0.f, 0.f, 0.f, 0.f};

    int ar = tid >> 2;                 // A row 0..63
    int aq = tid & 3;                  // 8-k chunk within 32-k tile
    float anrm = norm_in[(m0 + ar) >> 1];
    const float* ap = A + (size_t)(m0 + ar) * KP;
    const uint4* Whv = (const uint4*)Wh;   // row stride 32 uint4
    const uint4* Wlv = (const uint4*)Wl;

    for (int t0 = 0; t0 < NT; ++t0) {
        int kg0 = t0 * 32 + aq * 8;
        // ---- stage A: 8 fp32, fuse norm_in, split to f16 hi/lo (no bounds: pads zero)
        float4 f0 = *(const float4*)(ap + kg0);
        float4 f1 = *(const float4*)(ap + kg0 + 4);
        float x[8] = {f0.x, f0.y, f0.z, f0.w, f1.x, f1.y, f1.z, f1.w};
        f16x8 vh, vl;
#pragma unroll
        for (int j = 0; j < 8; ++j) {
            float v = x[j] * anrm;
            _Float16 h = (_Float16)v;
            vh[j] = h;
            vl[j] = (_Float16)(v - (float)h);
        }
        *(f16x8*)&Ah_s[ar][aq * 8] = vh;
        *(f16x8*)&Al_s[ar][aq * 8] = vl;
        // ---- stage B: 128 rows x 32 k, hi+lo (2 uint4/thread each)
#pragma unroll
        for (int it = 0; it < 2; ++it) {
            int f = it * 256 + tid;
            int rn = f >> 2, q = f & 3;
            size_t base = (size_t)(n0 + rn) * 32 + t0 * 4 + q;
            *(uint4*)&Bh_s[rn][q * 8] = Whv[base];
            *(uint4*)&Bl_s[rn][q * 8] = Wlv[base];
        }
        __syncthreads();

        f16x8 ah[2], al[2], bh[4], bl[4];
#pragma unroll
        for (int mi = 0; mi < 2; ++mi) {
            ah[mi] = *(const f16x8*)&Ah_s[wm * 32 + mi * 16 + lr][quad * 8];
            al[mi] = *(const f16x8*)&Al_s[wm * 32 + mi * 16 + lr][quad * 8];
        }
#pragma unroll
        for (int ni = 0; ni < 4; ++ni) {
            bh[ni] = *(const f16x8*)&Bh_s[wn * 64 + ni * 16 + lr][quad * 8];
            bl[ni] = *(const f16x8*)&Bl_s[wn * 64 + ni * 16 + lr][quad * 8];
        }
#pragma unroll
        for (int mi = 0; mi < 2; ++mi)
#pragma unroll
            for (int ni = 0; ni < 4; ++ni) {
                acc[mi][ni] = __builtin_amdgcn_mfma_f32_16x16x32_f16(ah[mi], bh[ni], acc[mi][ni], 0, 0, 0);
                acc[mi][ni] = __builtin_amdgcn_mfma_f32_16x16x32_f16(al[mi], bh[ni], acc[mi][ni], 0, 0, 0);
                acc[mi][ni] = __builtin_amdgcn_mfma_f32_16x16x32_f16(ah[mi], bl[ni], acc[mi][ni], 0, 0, 0);
            }
        __syncthreads();
    }

    if (FUSE) {
        float* out = (float*)outv;
#pragma unroll
        for (int mi = 0; mi < 2; ++mi) {
#pragma unroll
            for (int i = 0; i < 4; ++i) {
                float p = 0.f;
#pragma unroll
                for (int ni = 0; ni < 4; ++ni) {
                    int c = n0 + wn * 64 + ni * 16 + lr;
                    if (c < 246)
                        p += fmaxf(acc[mi][ni][i] + b[c], 0.f) * fcw[c];
                }
#pragma unroll
                for (int off = 8; off > 0; off >>= 1)
                    p += __shfl_down(p, off, 16);
                if (lr == 0) {
                    int m = m0 + wm * 32 + mi * 16 + quad * 4 + i;
                    atomicAdd(&out[m >> 1], 0.5f * p);
                }
            }
        }
    } else {
        float* outF = (float*)outv;    // fp32 [M][256]; cols>=246 get 0 (acc=0, bj=0)
#pragma unroll
        for (int ni = 0; ni < 4; ++ni) {
            int c = n0 + wn * 64 + ni * 16 + lr;
            float bj = (c < 246) ? b[c] : 0.f;
#pragma unroll
            for (int mi = 0; mi < 2; ++mi)
#pragma unroll
                for (int i = 0; i < 4; ++i) {
                    int m = m0 + wm * 32 + mi * 16 + quad * 4 + i;
                    outF[(size_t)m * 256 + c] = fmaxf(acc[mi][ni][i] + bj, 0.f);
                }
        }
    }
}

extern "C" void kernel_launch(void* const* d_in, const int* in_sizes, int n_in,
                              void* d_out, int out_size, void* d_ws, size_t ws_size,
                              hipStream_t stream) {
    const float* feat = (const float*)d_in[0];
    const int*   src  = (const int*)d_in[1];
    const int*   dst  = (const int*)d_in[2];
    const float* W0   = (const float*)d_in[3];
    const float* b0   = (const float*)d_in[4];
    const float* W1   = (const float*)d_in[5];
    const float* b1   = (const float*)d_in[6];
    const float* W2   = (const float*)d_in[7];
    const float* b2   = (const float*)d_in[8];
    const float* fcw  = (const float*)d_in[9];
    const float* fcb  = (const float*)d_in[10];
    float* out = (float*)d_out;

    char* ws = (char*)d_ws;
    size_t off = 0;
    auto alloc = [&](size_t bytes) {
        void* p = ws + off;
        off = (off + bytes + 255) & ~(size_t)255;
        return p;
    };
    int*    deg_out_i = (int*)alloc((2 * NN + 64) * sizeof(int));
    int*    deg_in_i  = deg_out_i + NN;
    int*    counter   = deg_out_i + 2 * NN;
    int*    row_start = (int*)alloc(NN * sizeof(int));
    int*    cursor    = (int*)alloc(NN * sizeof(int));
    int*    sorted    = (int*)alloc(NE * sizeof(int));
    float*  norm_out  = (float*)alloc(NN * sizeof(float));
    float*  norm_in   = (float*)alloc(NN * sizeof(float));
    ushort* Wh0 = (ushort*)alloc(256 * 256 * sizeof(ushort));
    ushort* Wl0 = (ushort*)alloc(256 * 256 * sizeof(ushort));
    ushort* Wh1 = (ushort*)alloc(256 * 256 * sizeof(ushort));
    ushort* Wl1 = (ushort*)alloc(256 * 256 * sizeof(ushort));
    ushort* Wh2 = (ushort*)alloc(256 * 256 * sizeof(ushort));
    ushort* Wl2 = (ushort*)alloc(256 * 256 * sizeof(ushort));
    float*  bufA = (float*)alloc((size_t)NN * SS * 256 * sizeof(float));  // agg out (padded)
    float*  bufH = (float*)alloc((size_t)NN * SS * 256 * sizeof(float));  // gemm out (padded)

    hipMemsetAsync(deg_out_i, 0, (2 * NN + 1) * sizeof(int), stream);

    degree_kernel<<<(NE + 255) / 256, 256, 0, stream>>>(src, dst, deg_out_i, deg_in_i);
    norm_kernel<<<(NN + 255) / 256, 256, 0, stream>>>(deg_out_i, deg_in_i, norm_out, norm_in);
    alloc_kernel<<<(NN + 255) / 256, 256, 0, stream>>>(deg_in_i, row_start, cursor, counter);
    scatter_kernel<<<(NE + 255) / 256, 256, 0, stream>>>(src, dst, cursor, sorted);

    convert_w_split<<<256, 256, 0, stream>>>(W0, Wh0, Wl0, FIN);
    convert_w_split<<<256, 256, 0, stream>>>(W1, Wh1, Wl1, FH);
    convert_w_split<<<256, 256, 0, stream>>>(W2, Wh2, Wl2, FH);
    init_out<<<(NN + 255) / 256, 256, 0, stream>>>(out, fcb);

    const int NB = (NN + 3) / 4;     // 5000
    dim3 ggrid(NN * SS / 64, 2);     // 625 x 2

    // Layer 0: feat [N][2*128] -> agg(bufA, stride 128) -> gemm -> h1(bufH, stride 256)
    aggregate2<64><<<dim3(NB, 2), 128, 0, stream>>>(feat, row_start, deg_in_i, sorted, norm_out, bufA);
    gemm_split<FIN, false><<<ggrid, 256, 0, stream>>>(bufA, Wh0, Wl0, b0, norm_in, bufH, fcw);

    // Layer 1: h1 -> agg(bufA, stride 256) -> gemm -> h2(bufH)
    aggregate2<128><<<dim3(NB, 4), 128, 0, stream>>>(bufH, row_start, deg_in_i, sorted, norm_out, bufA);
    gemm_split<256, false><<<ggrid, 256, 0, stream>>>(bufA, Wh1, Wl1, b1, norm_in, bufH, fcw);

    // Layer 2: h2 -> agg(bufA) -> fused gemm -> out (atomicAdd; out pre-set to fcb)
    aggregate2<128><<<dim3(NB, 4), 128, 0, stream>>>(bufH, row_start, deg_in_i, sorted, norm_out, bufA);
    gemm_split<256, true><<<ggrid, 256, 0, stream>>>(bufA, Wh2, Wl2, b2, norm_in, out, fcw);
}